// Round 13
// baseline (154.068 us; speedup 1.0000x reference)
//
#include <hip/hip_runtime.h>
#include <hip/hip_bf16.h>

// Spectral attention: B=2, N=50000, D=256, H=8, Dh=32, K_EIG=32, NUM_BANDS=3
// Key identity: Qf = E^T (x Wq^T + bq) = (E^T x) Wq^T + s * bq, s[k] = sum_n E[n,k]
// N-sized work: U = E^T x (read x once) and out = E @ out_freq (write out once).
// Lessons: r2 arrays spill (named regs only); r3 no redundant HBM x reads;
// r4 >=4 blocks/CU; r6 deep prefetch on the x stream; r7 waves own disjoint
// x rows; r8 never set launch_bounds min-waves (spill = WRITE_SIZE blowup);
// r9 LDS instr count is a shared per-CU pipe floor; r10 E is cache-resident,
// no LDS staging; r11 E row loads are a dependent-load stall -> double-buffer
// E one row ahead; r12 P##0.x pastes as pp-number "0.x" -> use P##_0 names.

constexpr int D = 256;   // d_model

// ---------------------------------------------------------------- k_colsum
__global__ __launch_bounds__(256) void k_colsum(const float* __restrict__ E,
                                                float* __restrict__ pS, int N) {
  int k = threadIdx.x & 31;
  int rg = threadIdx.x >> 5;
  int rs = (N + 255) >> 8;
  int n0 = blockIdx.x * rs;
  int n1 = n0 + rs; if (n1 > N) n1 = N;
  float acc = 0.f;
  for (int n = n0 + rg; n < n1; n += 8) acc += E[(size_t)n * 32 + k];
  __shared__ float red[256];
  red[threadIdx.x] = acc;
  __syncthreads();
  if (threadIdx.x < 32) {
    float t = red[threadIdx.x];
#pragma unroll
    for (int i = 1; i < 8; ++i) t += red[i * 32 + threadIdx.x];
    pS[blockIdx.x * 32 + threadIdx.x] = t;
  }
}

// ---------------------------------------------------------------- k_partial
// grid = B*nchunk, 256 thr = 4 waves: dh = w&1 (d-half), rp = w>>1 (row
// parity, disjoint rows). Lane owns d-pair. 32 float2 named accs. E rows via
// uniform loads double-buffered one row ahead (Ea_/Eb_); x 8-deep prefetch.
// 2-pass LDS reduce across row-parity -> pU[bc][32][256].
__global__ __launch_bounds__(256) void k_partial(const float* __restrict__ x,
                                                 const float* __restrict__ E,
                                                 float* __restrict__ pU,
                                                 int N, int nchunk, int rpc) {
  int bc = blockIdx.x;                     // b*nchunk + c
  int c = bc % nchunk;
  int b = bc / nchunk;
  int t = threadIdx.x;
  int w = t >> 6;
  int dh = w & 1;                          // d-half
  int rp = w >> 1;                         // row parity
  int lane = t & 63;
  int n0 = c * rpc;
  int n1 = n0 + rpc; if (n1 > N) n1 = N;
  int nrows = n1 - n0; if (nrows < 0) nrows = 0;

  float2 a0={0,0},a1={0,0},a2={0,0},a3={0,0},a4={0,0},a5={0,0},a6={0,0},a7={0,0};
  float2 a8={0,0},a9={0,0},a10={0,0},a11={0,0},a12={0,0},a13={0,0},a14={0,0},a15={0,0};
  float2 a16={0,0},a17={0,0},a18={0,0},a19={0,0},a20={0,0},a21={0,0},a22={0,0},a23={0,0};
  float2 a24={0,0},a25={0,0},a26={0,0},a27={0,0},a28={0,0},a29={0,0},a30={0,0},a31={0,0};

  int mrows = (nrows > rp) ? ((nrows - rp + 1) >> 1) : 0;

  if (mrows > 0) {
    const float* xb = x + (size_t)b * N * D + dh * 128 + 2 * lane;
#define RIDX(j) (n0 + rp + 2 * ((j) < mrows ? (j) : mrows - 1))
#define XLD(j) (*reinterpret_cast<const float2*>(xb + (size_t)RIDX(j) * D))
#define ELD(P, j) { const float4* Er = reinterpret_cast<const float4*>( \
      E + (size_t)RIDX(j) * 32);                                        \
    P##_0 = Er[0]; P##_1 = Er[1]; P##_2 = Er[2]; P##_3 = Er[3];         \
    P##_4 = Er[4]; P##_5 = Er[5]; P##_6 = Er[6]; P##_7 = Er[7]; }

    float2 p0 = XLD(0), p1 = XLD(1), p2 = XLD(2), p3 = XLD(3);
    float2 p4 = XLD(4), p5 = XLD(5), p6 = XLD(6), p7 = XLD(7);
    float4 Ea_0, Ea_1, Ea_2, Ea_3, Ea_4, Ea_5, Ea_6, Ea_7;
    float4 Eb_0, Eb_1, Eb_2, Eb_3, Eb_4, Eb_5, Eb_6, Eb_7;
    ELD(Ea, 0)

#define FK2(s, A) { A.x = fmaf(s, xq.x, A.x); A.y = fmaf(s, xq.y, A.y); }
#define FMA32(P, q) { float2 xq = q;                                        \
    FK2(P##_0.x, a0)  FK2(P##_0.y, a1)  FK2(P##_0.z, a2)  FK2(P##_0.w, a3)  \
    FK2(P##_1.x, a4)  FK2(P##_1.y, a5)  FK2(P##_1.z, a6)  FK2(P##_1.w, a7)  \
    FK2(P##_2.x, a8)  FK2(P##_2.y, a9)  FK2(P##_2.z, a10) FK2(P##_2.w, a11) \
    FK2(P##_3.x, a12) FK2(P##_3.y, a13) FK2(P##_3.z, a14) FK2(P##_3.w, a15) \
    FK2(P##_4.x, a16) FK2(P##_4.y, a17) FK2(P##_4.z, a18) FK2(P##_4.w, a19) \
    FK2(P##_5.x, a20) FK2(P##_5.y, a21) FK2(P##_5.z, a22) FK2(P##_5.w, a23) \
    FK2(P##_6.x, a24) FK2(P##_6.y, a25) FK2(P##_6.z, a26) FK2(P##_6.w, a27) \
    FK2(P##_7.x, a28) FK2(P##_7.y, a29) FK2(P##_7.z, a30) FK2(P##_7.w, a31) }

    int j = 0;
#pragma unroll 1
    for (; j + 8 <= mrows; j += 8) {
      ELD(Eb, j + 1) FMA32(Ea, p0) p0 = XLD(j + 8);
      ELD(Ea, j + 2) FMA32(Eb, p1) p1 = XLD(j + 9);
      ELD(Eb, j + 3) FMA32(Ea, p2) p2 = XLD(j + 10);
      ELD(Ea, j + 4) FMA32(Eb, p3) p3 = XLD(j + 11);
      ELD(Eb, j + 5) FMA32(Ea, p4) p4 = XLD(j + 12);
      ELD(Ea, j + 6) FMA32(Eb, p5) p5 = XLD(j + 13);
      ELD(Eb, j + 7) FMA32(Ea, p6) p6 = XLD(j + 14);
      ELD(Ea, j + 8) FMA32(Eb, p7) p7 = XLD(j + 15);
    }
    // tail: Ea holds row j (clamped loads in the loop preserved this)
    if (j + 0 < mrows) { ELD(Eb, j + 1) FMA32(Ea, p0) }
    if (j + 1 < mrows) { ELD(Ea, j + 2) FMA32(Eb, p1) }
    if (j + 2 < mrows) { ELD(Eb, j + 3) FMA32(Ea, p2) }
    if (j + 3 < mrows) { ELD(Ea, j + 4) FMA32(Eb, p3) }
    if (j + 4 < mrows) { ELD(Eb, j + 5) FMA32(Ea, p4) }
    if (j + 5 < mrows) { ELD(Ea, j + 6) FMA32(Eb, p5) }
    if (j + 6 < mrows) { FMA32(Ea, p6) }
#undef FMA32
#undef FK2
#undef ELD
#undef XLD
#undef RIDX
  }

  // 2-pass cross-parity reduce: rp=1 stages 16 k's, rp=0 adds + stores.
  __shared__ float2 buf[2][16][64];        // 16 KB
  float* o = pU + (size_t)bc * 8192 + dh * 128 + 2 * lane;

#define PASS(base, A0, A1, A2, A3, A4, A5, A6, A7,                  \
             A8, A9, A10, A11, A12, A13, A14, A15)                  \
  __syncthreads();                                                  \
  if (rp == 1) {                                                    \
    buf[dh][ 0][lane] = A0;  buf[dh][ 1][lane] = A1;                \
    buf[dh][ 2][lane] = A2;  buf[dh][ 3][lane] = A3;                \
    buf[dh][ 4][lane] = A4;  buf[dh][ 5][lane] = A5;                \
    buf[dh][ 6][lane] = A6;  buf[dh][ 7][lane] = A7;                \
    buf[dh][ 8][lane] = A8;  buf[dh][ 9][lane] = A9;                \
    buf[dh][10][lane] = A10; buf[dh][11][lane] = A11;               \
    buf[dh][12][lane] = A12; buf[dh][13][lane] = A13;               \
    buf[dh][14][lane] = A14; buf[dh][15][lane] = A15;               \
  }                                                                 \
  __syncthreads();                                                  \
  if (rp == 0) {                                                    \
    float2 s;                                                       \
    s = buf[dh][ 0][lane]; A0.x += s.x; A0.y += s.y;                \
    *reinterpret_cast<float2*>(o + ((base) +  0) * 256) = A0;       \
    s = buf[dh][ 1][lane]; A1.x += s.x; A1.y += s.y;                \
    *reinterpret_cast<float2*>(o + ((base) +  1) * 256) = A1;       \
    s = buf[dh][ 2][lane]; A2.x += s.x; A2.y += s.y;                \
    *reinterpret_cast<float2*>(o + ((base) +  2) * 256) = A2;       \
    s = buf[dh][ 3][lane]; A3.x += s.x; A3.y += s.y;                \
    *reinterpret_cast<float2*>(o + ((base) +  3) * 256) = A3;       \
    s = buf[dh][ 4][lane]; A4.x += s.x; A4.y += s.y;                \
    *reinterpret_cast<float2*>(o + ((base) +  4) * 256) = A4;       \
    s = buf[dh][ 5][lane]; A5.x += s.x; A5.y += s.y;                \
    *reinterpret_cast<float2*>(o + ((base) +  5) * 256) = A5;       \
    s = buf[dh][ 6][lane]; A6.x += s.x; A6.y += s.y;                \
    *reinterpret_cast<float2*>(o + ((base) +  6) * 256) = A6;       \
    s = buf[dh][ 7][lane]; A7.x += s.x; A7.y += s.y;                \
    *reinterpret_cast<float2*>(o + ((base) +  7) * 256) = A7;       \
    s = buf[dh][ 8][lane]; A8.x += s.x; A8.y += s.y;                \
    *reinterpret_cast<float2*>(o + ((base) +  8) * 256) = A8;       \
    s = buf[dh][ 9][lane]; A9.x += s.x; A9.y += s.y;                \
    *reinterpret_cast<float2*>(o + ((base) +  9) * 256) = A9;       \
    s = buf[dh][10][lane]; A10.x += s.x; A10.y += s.y;              \
    *reinterpret_cast<float2*>(o + ((base) + 10) * 256) = A10;      \
    s = buf[dh][11][lane]; A11.x += s.x; A11.y += s.y;              \
    *reinterpret_cast<float2*>(o + ((base) + 11) * 256) = A11;      \
    s = buf[dh][12][lane]; A12.x += s.x; A12.y += s.y;              \
    *reinterpret_cast<float2*>(o + ((base) + 12) * 256) = A12;      \
    s = buf[dh][13][lane]; A13.x += s.x; A13.y += s.y;              \
    *reinterpret_cast<float2*>(o + ((base) + 13) * 256) = A13;      \
    s = buf[dh][14][lane]; A14.x += s.x; A14.y += s.y;              \
    *reinterpret_cast<float2*>(o + ((base) + 14) * 256) = A14;      \
    s = buf[dh][15][lane]; A15.x += s.x; A15.y += s.y;              \
    *reinterpret_cast<float2*>(o + ((base) + 15) * 256) = A15;      \
  }

  PASS(0,  a0,  a1,  a2,  a3,  a4,  a5,  a6,  a7,
           a8,  a9,  a10, a11, a12, a13, a14, a15)
  PASS(16, a16, a17, a18, a19, a20, a21, a22, a23,
           a24, a25, a26, a27, a28, a29, a30, a31)
#undef PASS
}

// ---------------------------------------------------------------- k_reduce
// U[b,kd] = sum_c pU[b][c][kd]; 512 blocks, 8 subs x 8 indep accumulators.
__global__ __launch_bounds__(256) void k_reduce(const float* __restrict__ pU,
                                                float* __restrict__ U, int nchunk) {
  int e = blockIdx.x * 32 + (threadIdx.x & 31);
  int sub = threadIdx.x >> 5;              // 0..7
  int b = e >> 13;
  int kd = e & 8191;
  const float* p = pU + (size_t)b * nchunk * 8192 + kd;
  float a0 = 0.f, a1 = 0.f, a2 = 0.f, a3 = 0.f;
  float a4 = 0.f, a5 = 0.f, a6 = 0.f, a7 = 0.f;
  int c = sub;
#pragma unroll 1
  for (; c + 56 < nchunk; c += 64) {
    a0 += p[(size_t)c * 8192];
    a1 += p[(size_t)(c + 8) * 8192];
    a2 += p[(size_t)(c + 16) * 8192];
    a3 += p[(size_t)(c + 24) * 8192];
    a4 += p[(size_t)(c + 32) * 8192];
    a5 += p[(size_t)(c + 40) * 8192];
    a6 += p[(size_t)(c + 48) * 8192];
    a7 += p[(size_t)(c + 56) * 8192];
  }
  for (; c < nchunk; c += 8) a0 += p[(size_t)c * 8192];
  __shared__ float red[256];
  red[threadIdx.x] = ((a0 + a1) + (a2 + a3)) + ((a4 + a5) + (a6 + a7));
  __syncthreads();
  if (threadIdx.x < 32) {
    float s = red[threadIdx.x];
#pragma unroll
    for (int i = 1; i < 8; ++i) s += red[i * 32 + threadIdx.x];
    U[e] = s;
  }
}

// ---------------------------------------------------------------- k_project
__global__ __launch_bounds__(256) void k_project(
    const float* __restrict__ U, const float* __restrict__ pS,
    const float* __restrict__ Wq, const float* __restrict__ bq,
    const float* __restrict__ Wk, const float* __restrict__ bk,
    const float* __restrict__ Wv, const float* __restrict__ bv,
    const float* __restrict__ ev, const float* __restrict__ bb,
    const float* __restrict__ fw,
    float* __restrict__ Qfg, float* __restrict__ Kfg, float* __restrict__ Vfg) {
  int blk = blockIdx.x;                    // b*32 + k
  int k = blk & 31;
  int t = threadIdx.x;
  __shared__ __align__(16) float u[256];
  __shared__ float red[256];
  u[t] = U[(size_t)blk * 256 + t];
  red[t] = pS[t * 32 + k];
  __syncthreads();
#pragma unroll
  for (int off = 128; off > 0; off >>= 1) {
    if (t < off) red[t] += red[t + off];
    __syncthreads();
  }
  float sk = red[0];

  // filter response — FP64 to match numpy ref branch semantics
  float mnf = ev[0], mxf = ev[0];
#pragma unroll
  for (int i = 1; i < 32; ++i) { float v = ev[i]; mnf = fminf(mnf, v); mxf = fmaxf(mxf, v); }
  double mn = (double)mnf, mx = (double)mxf;
  double lam = ((double)ev[k] - mn) / (mx - mn + 1e-8);
  int h = t >> 5;
  float g = 0.f;
#pragma unroll
  for (int i = 0; i < 3; ++i) {
    double lo = (double)bb[h * 4 + i], hi = (double)bb[h * 4 + i + 1];
    if (lam >= lo && lam < hi) g = fw[(h * 3 + i) * 32 + k];
  }

  const float4* u4 = reinterpret_cast<const float4*>(u);
  const float4* wq4 = reinterpret_cast<const float4*>(Wq) + (size_t)t * 64;
  const float4* wk4 = reinterpret_cast<const float4*>(Wk) + (size_t)t * 64;
  const float4* wv4 = reinterpret_cast<const float4*>(Wv) + (size_t)t * 64;
  float aq = 0.f, ak = 0.f, av = 0.f;
#pragma unroll 4
  for (int j = 0; j < 64; ++j) {
    float4 uv = u4[j];
    float4 q = wq4[j], kk = wk4[j], vv = wv4[j];
    aq = fmaf(uv.x, q.x, aq);  aq = fmaf(uv.y, q.y, aq);
    aq = fmaf(uv.z, q.z, aq);  aq = fmaf(uv.w, q.w, aq);
    ak = fmaf(uv.x, kk.x, ak); ak = fmaf(uv.y, kk.y, ak);
    ak = fmaf(uv.z, kk.z, ak); ak = fmaf(uv.w, kk.w, ak);
    av = fmaf(uv.x, vv.x, av); av = fmaf(uv.y, vv.y, av);
    av = fmaf(uv.z, vv.z, av); av = fmaf(uv.w, vv.w, av);
  }
  Qfg[(size_t)blk * 256 + t] = (aq + bq[t] * sk) * g;
  Kfg[(size_t)blk * 256 + t] = (ak + bk[t] * sk) * g;
  Vfg[(size_t)blk * 256 + t] = (av + bv[t] * sk) * g;
}

// ---------------------------------------------------------------- k_attn
__global__ __launch_bounds__(1024) void k_attn(const float* __restrict__ Qfg,
                                               const float* __restrict__ Kfg,
                                               const float* __restrict__ Vfg,
                                               float* __restrict__ of) {
  int blk = blockIdx.x;                    // b*8 + h
  int b = blk >> 3, h = blk & 7;
  int tid = threadIdx.x;
  int row = tid >> 5, col = tid & 31;
  __shared__ float Q[32][33], Kt[32][33], V[32][33], A[32][33];
  size_t base = (size_t)b * 32 * 256 + h * 32;
  Q[row][col]  = Qfg[base + row * 256 + col];
  Kt[row][col] = Kfg[base + row * 256 + col];
  V[row][col]  = Vfg[base + row * 256 + col];
  __syncthreads();
  float sc = 0.f;
#pragma unroll
  for (int d0 = 0; d0 < 32; ++d0) sc = fmaf(Q[row][d0], Kt[col][d0], sc);
  sc *= 0.17677669529663687f;              // 1/sqrt(32)
  float m = sc;
#pragma unroll
  for (int o = 16; o > 0; o >>= 1) m = fmaxf(m, __shfl_xor(m, o, 32));
  float p = expf(sc - m);
  float su = p;
#pragma unroll
  for (int o = 16; o > 0; o >>= 1) su += __shfl_xor(su, o, 32);
  A[row][col] = p / su;
  __syncthreads();
  float o_ = 0.f;
#pragma unroll
  for (int l = 0; l < 32; ++l) o_ = fmaf(A[row][l], V[l][col], o_);
  of[base + row * 256 + col] = o_;
}

// ---------------------------------------------------------------- k_expand
// out[b,n,d] = sum_k E[n,k] * of[b,k,d]. 4 waves (bb = w&1 batch, dh = w>>1
// d-half); lane owns d-pair. of in 32 float2 regs; E rows uniform-loaded and
// double-buffered one row ahead (Ea_/Eb_). float2 stores.
__global__ __launch_bounds__(256) void k_expand(const float* __restrict__ E,
                                                const float* __restrict__ of,
                                                float* __restrict__ out,
                                                int N, int rows) {
  int n0 = blockIdx.x * rows;
  int n1 = n0 + rows; if (n1 > N) n1 = N;
  if (n1 <= n0) return;
  int t = threadIdx.x;
  int w = t >> 6;
  int bb = w & 1;                          // batch
  int dh = w >> 1;                         // d-half
  int lane = t & 63;

  const float* ofb = of + (size_t)bb * 8192 + dh * 128 + 2 * lane;
#define LDF(i) float2 f##i = *reinterpret_cast<const float2*>(ofb + (i) * 256);
  LDF(0)  LDF(1)  LDF(2)  LDF(3)  LDF(4)  LDF(5)  LDF(6)  LDF(7)
  LDF(8)  LDF(9)  LDF(10) LDF(11) LDF(12) LDF(13) LDF(14) LDF(15)
  LDF(16) LDF(17) LDF(18) LDF(19) LDF(20) LDF(21) LDF(22) LDF(23)
  LDF(24) LDF(25) LDF(26) LDF(27) LDF(28) LDF(29) LDF(30) LDF(31)
#undef LDF

  float* ob = out + (size_t)bb * N * D + dh * 128 + 2 * lane;

#define CLMP(nn) ((nn) < n1 - 1 ? (nn) : n1 - 1)
#define ELD(P, nn) { const float4* Er = reinterpret_cast<const float4*>( \
      E + (size_t)CLMP(nn) * 32);                                        \
    P##_0 = Er[0]; P##_1 = Er[1]; P##_2 = Er[2]; P##_3 = Er[3];          \
    P##_4 = Er[4]; P##_5 = Er[5]; P##_6 = Er[6]; P##_7 = Er[7]; }
#define EX(s, fk, A) { A.x = fmaf(s, fk.x, A.x); A.y = fmaf(s, fk.y, A.y); }
#define EXPROW(P, nn) {                                                  \
    float2 oA = {0.f, 0.f}, oB = {0.f, 0.f};                             \
    EX(P##_0.x, f0,  oA) EX(P##_0.y, f1,  oB) EX(P##_0.z, f2,  oA) EX(P##_0.w, f3,  oB) \
    EX(P##_1.x, f4,  oA) EX(P##_1.y, f5,  oB) EX(P##_1.z, f6,  oA) EX(P##_1.w, f7,  oB) \
    EX(P##_2.x, f8,  oA) EX(P##_2.y, f9,  oB) EX(P##_2.z, f10, oA) EX(P##_2.w, f11, oB) \
    EX(P##_3.x, f12, oA) EX(P##_3.y, f13, oB) EX(P##_3.z, f14, oA) EX(P##_3.w, f15, oB) \
    EX(P##_4.x, f16, oA) EX(P##_4.y, f17, oB) EX(P##_4.z, f18, oA) EX(P##_4.w, f19, oB) \
    EX(P##_5.x, f20, oA) EX(P##_5.y, f21, oB) EX(P##_5.z, f22, oA) EX(P##_5.w, f23, oB) \
    EX(P##_6.x, f24, oA) EX(P##_6.y, f25, oB) EX(P##_6.z, f26, oA) EX(P##_6.w, f27, oB) \
    EX(P##_7.x, f28, oA) EX(P##_7.y, f29, oB) EX(P##_7.z, f30, oA) EX(P##_7.w, f31, oB) \
    float2 o2; o2.x = oA.x + oB.x; o2.y = oA.y + oB.y;                   \
    *reinterpret_cast<float2*>(ob + (size_t)(nn) * D) = o2; }

  float4 Ea_0, Ea_1, Ea_2, Ea_3, Ea_4, Ea_5, Ea_6, Ea_7;
  float4 Eb_0, Eb_1, Eb_2, Eb_3, Eb_4, Eb_5, Eb_6, Eb_7;
  ELD(Ea, n0)
  int n = n0;
#pragma unroll 1
  for (; n + 2 <= n1; n += 2) {
    ELD(Eb, n + 1)
    EXPROW(Ea, n)
    ELD(Ea, n + 2)
    EXPROW(Eb, n + 1)
  }
  if (n < n1) EXPROW(Ea, n)
#undef EXPROW
#undef EX
#undef ELD
#undef CLMP
}

// ---------------------------------------------------------------- launch
extern "C" void kernel_launch(void* const* d_in, const int* in_sizes, int n_in,
                              void* d_out, int out_size, void* d_ws, size_t ws_size,
                              hipStream_t stream) {
  const float* x  = (const float*)d_in[0];
  const float* E  = (const float*)d_in[1];
  const float* ev = (const float*)d_in[2];
  const float* Wq = (const float*)d_in[3];
  const float* bq = (const float*)d_in[4];
  const float* Wk = (const float*)d_in[5];
  const float* bk = (const float*)d_in[6];
  const float* Wv = (const float*)d_in[7];
  const float* bv = (const float*)d_in[8];
  const float* bb = (const float*)d_in[9];
  const float* fw = (const float*)d_in[10];
  float* out = (float*)d_out;
  float* ws  = (float*)d_ws;

  const int N = in_sizes[1] / 32;          // 50000
  const int B = in_sizes[0] / (N * 256);   // 2

  // workspace layout (floats)
  float* U   = ws;                         // B*32*256 = 16384
  float* Qfg = ws + 16384;
  float* Kfg = ws + 32768;
  float* Vfg = ws + 49152;
  float* of  = ws + 65536;
  float* pS  = ws + 81920;                 // 256*32 = 8192
  float* pU  = ws + 90112;                 // B*nchunk*8192 floats

  // nchunk = 512 -> grid 1024 blocks x 4 waves = 16 waves/CU; pU 33.6 MB.
  int nchunk = 512;
  if ((90112 + (size_t)B * nchunk * 8192) * sizeof(float) > ws_size) nchunk = 256;
  int rpc = (N + nchunk - 1) / nchunk;

  k_colsum<<<256, 256, 0, stream>>>(E, pS, N);
  k_partial<<<B * nchunk, 256, 0, stream>>>(x, E, pU, N, nchunk, rpc);
  k_reduce<<<B * 8192 / 32, 256, 0, stream>>>(pU, U, nchunk);
  k_project<<<B * 32, 256, 0, stream>>>(U, pS, Wq, bq, Wk, bk, Wv, bv,
                                        ev, bb, fw, Qfg, Kfg, Vfg);
  k_attn<<<B * 8, 1024, 0, stream>>>(Qfg, Kfg, Vfg, of);
  int rows = 50;
  int nbr = (N + rows - 1) / rows;
  k_expand<<<nbr, 256, 0, stream>>>(E, of, out, N, rows);
}

// Round 14
// 146.024 us; speedup vs baseline: 1.0551x; 1.0551x over previous
//
#include <hip/hip_runtime.h>
#include <hip/hip_bf16.h>

// Spectral attention: B=2, N=50000, D=256, H=8, Dh=32, K_EIG=32, NUM_BANDS=3
// Key identity: Qf = E^T (x Wq^T + bq) = (E^T x) Wq^T + s * bq, s[k] = sum_n E[n,k]
// N-sized work: U = E^T x (read x once) and out = E @ out_freq (write out once).
// Lessons: r2 arrays spill; r3 no redundant HBM reads; r4 >=4 blocks/CU;
// r8 never set launch_bounds min-waves; r9 LDS instrs are a shared pipe;
// r10 E is cache-resident; r13 (KEY): E loads and x loads share the FIFO
// vmcnt counter -> any per-row E-load wait drains ALL older x prefetches.
// Fix: tile x+E through double-buffered LDS; one vmcnt chokepoint per tile;
// consumption is ds_read (lgkmcnt), fully decoupled from the global stream.

constexpr int D = 256;   // d_model

// ---------------------------------------------------------------- k_colsum
__global__ __launch_bounds__(256) void k_colsum(const float* __restrict__ E,
                                                float* __restrict__ pS, int N) {
  int k = threadIdx.x & 31;
  int rg = threadIdx.x >> 5;
  int rs = (N + 255) >> 8;
  int n0 = blockIdx.x * rs;
  int n1 = n0 + rs; if (n1 > N) n1 = N;
  float acc = 0.f;
  for (int n = n0 + rg; n < n1; n += 8) acc += E[(size_t)n * 32 + k];
  __shared__ float red[256];
  red[threadIdx.x] = acc;
  __syncthreads();
  if (threadIdx.x < 32) {
    float t = red[threadIdx.x];
#pragma unroll
    for (int i = 1; i < 8; ++i) t += red[i * 32 + threadIdx.x];
    pS[blockIdx.x * 32 + threadIdx.x] = t;
  }
}

// ---------------------------------------------------------------- k_partial
// grid = B*nchunk, 256 thr = 4 waves. Wave w owns k-octet [8w,8w+8); lane owns
// d-quad. x (16 KB) + E (2 KB) tiles staged reg->LDS, double-buffered: one
// barrier + one vmcnt chokepoint per 16 rows; compute reads LDS only (lgkm).
// pU[bc][k][d] += E[n,k]*x[b,n,d]; waves own disjoint k -> no cross-reduce.
__global__ __launch_bounds__(256) void k_partial(const float* __restrict__ x,
                                                 const float* __restrict__ E,
                                                 float* __restrict__ pU,
                                                 int N, int nchunk, int rpc) {
  int bc = blockIdx.x;                     // b*nchunk + c
  int c = bc % nchunk;
  int b = bc / nchunk;
  int t = threadIdx.x;
  int w = t >> 6;                          // wave -> k-octet
  int lane = t & 63;
  int n0 = c * rpc;
  int n1 = n0 + rpc; if (n1 > N) n1 = N;
  int nrows = n1 - n0; if (nrows < 0) nrows = 0;

  __shared__ __align__(16) float4 xs[2][1024];   // [buf][row*64+q] 32 KB
  __shared__ __align__(16) float4 es[2][128];    // [buf][row*8+q]   4 KB

  float4 a0={0,0,0,0}, a1={0,0,0,0}, a2={0,0,0,0}, a3={0,0,0,0};
  float4 a4={0,0,0,0}, a5={0,0,0,0}, a6={0,0,0,0}, a7={0,0,0,0};

  if (nrows > 0) {
    const float4* g4 = reinterpret_cast<const float4*>(x) + (size_t)b * N * 64;
    const float4* e4 = reinterpret_cast<const float4*>(E);
    int xr = t >> 6;                       // x staging: base row 0..3
    int xq = t & 63;                       //            float4 within row
    int er = t >> 3;                       // E staging (t<128): row 0..15
    int eq = t & 7;                        //            float4 within row

    float4 rx0, rx1, rx2, rx3, re;
#define CL(r) ((r) < N - 1 ? (r) : N - 1)
    {
      rx0 = g4[(size_t)CL(n0 + xr +  0) * 64 + xq];
      rx1 = g4[(size_t)CL(n0 + xr +  4) * 64 + xq];
      rx2 = g4[(size_t)CL(n0 + xr +  8) * 64 + xq];
      rx3 = g4[(size_t)CL(n0 + xr + 12) * 64 + xq];
      if (t < 128) re = e4[(size_t)CL(n0 + er) * 8 + eq];
    }
    int ntiles = (nrows + 15) >> 4;
#pragma unroll 1
    for (int tt = 0; tt < ntiles; ++tt) {
      int buf = tt & 1;
      // stage regs -> LDS (implicit vmcnt wait, covered by prev tile compute)
      xs[buf][(xr +  0) * 64 + xq] = rx0;
      xs[buf][(xr +  4) * 64 + xq] = rx1;
      xs[buf][(xr +  8) * 64 + xq] = rx2;
      xs[buf][(xr + 12) * 64 + xq] = rx3;
      if (t < 128) es[buf][t] = re;
      __syncthreads();
      if (tt + 1 < ntiles) {               // issue next tile's global loads
        int tb = n0 + ((tt + 1) << 4);
        rx0 = g4[(size_t)CL(tb + xr +  0) * 64 + xq];
        rx1 = g4[(size_t)CL(tb + xr +  4) * 64 + xq];
        rx2 = g4[(size_t)CL(tb + xr +  8) * 64 + xq];
        rx3 = g4[(size_t)CL(tb + xr + 12) * 64 + xq];
        if (t < 128) re = e4[(size_t)CL(tb + er) * 8 + eq];
      }
      int tr = nrows - (tt << 4); if (tr > 16) tr = 16;
#pragma unroll 4
      for (int r = 0; r < tr; ++r) {
        float4 xv = xs[buf][r * 64 + lane];          // per-lane b128
        float4 e0 = es[buf][r * 8 + 2 * w];          // broadcast
        float4 e1 = es[buf][r * 8 + 2 * w + 1];      // broadcast
        a0.x = fmaf(e0.x, xv.x, a0.x); a0.y = fmaf(e0.x, xv.y, a0.y);
        a0.z = fmaf(e0.x, xv.z, a0.z); a0.w = fmaf(e0.x, xv.w, a0.w);
        a1.x = fmaf(e0.y, xv.x, a1.x); a1.y = fmaf(e0.y, xv.y, a1.y);
        a1.z = fmaf(e0.y, xv.z, a1.z); a1.w = fmaf(e0.y, xv.w, a1.w);
        a2.x = fmaf(e0.z, xv.x, a2.x); a2.y = fmaf(e0.z, xv.y, a2.y);
        a2.z = fmaf(e0.z, xv.z, a2.z); a2.w = fmaf(e0.z, xv.w, a2.w);
        a3.x = fmaf(e0.w, xv.x, a3.x); a3.y = fmaf(e0.w, xv.y, a3.y);
        a3.z = fmaf(e0.w, xv.z, a3.z); a3.w = fmaf(e0.w, xv.w, a3.w);
        a4.x = fmaf(e1.x, xv.x, a4.x); a4.y = fmaf(e1.x, xv.y, a4.y);
        a4.z = fmaf(e1.x, xv.z, a4.z); a4.w = fmaf(e1.x, xv.w, a4.w);
        a5.x = fmaf(e1.y, xv.x, a5.x); a5.y = fmaf(e1.y, xv.y, a5.y);
        a5.z = fmaf(e1.y, xv.z, a5.z); a5.w = fmaf(e1.y, xv.w, a5.w);
        a6.x = fmaf(e1.z, xv.x, a6.x); a6.y = fmaf(e1.z, xv.y, a6.y);
        a6.z = fmaf(e1.z, xv.z, a6.z); a6.w = fmaf(e1.z, xv.w, a6.w);
        a7.x = fmaf(e1.w, xv.x, a7.x); a7.y = fmaf(e1.w, xv.y, a7.y);
        a7.z = fmaf(e1.w, xv.z, a7.z); a7.w = fmaf(e1.w, xv.w, a7.w);
      }
      __syncthreads();  // protect buf from next iteration's overwrite order
    }
#undef CL
  }

  float4* o4 = reinterpret_cast<float4*>(pU) + (size_t)bc * 2048
             + (size_t)(8 * w) * 64 + lane;
  o4[0 * 64] = a0; o4[1 * 64] = a1; o4[2 * 64] = a2; o4[3 * 64] = a3;
  o4[4 * 64] = a4; o4[5 * 64] = a5; o4[6 * 64] = a6; o4[7 * 64] = a7;
}

// ---------------------------------------------------------------- k_reduce
// U[b,kd] = sum_c pU[b][c][kd]; 512 blocks, 8 subs x 8 indep accumulators.
__global__ __launch_bounds__(256) void k_reduce(const float* __restrict__ pU,
                                                float* __restrict__ U, int nchunk) {
  int e = blockIdx.x * 32 + (threadIdx.x & 31);
  int sub = threadIdx.x >> 5;              // 0..7
  int b = e >> 13;
  int kd = e & 8191;
  const float* p = pU + (size_t)b * nchunk * 8192 + kd;
  float a0 = 0.f, a1 = 0.f, a2 = 0.f, a3 = 0.f;
  float a4 = 0.f, a5 = 0.f, a6 = 0.f, a7 = 0.f;
  int c = sub;
#pragma unroll 1
  for (; c + 56 < nchunk; c += 64) {
    a0 += p[(size_t)c * 8192];
    a1 += p[(size_t)(c + 8) * 8192];
    a2 += p[(size_t)(c + 16) * 8192];
    a3 += p[(size_t)(c + 24) * 8192];
    a4 += p[(size_t)(c + 32) * 8192];
    a5 += p[(size_t)(c + 40) * 8192];
    a6 += p[(size_t)(c + 48) * 8192];
    a7 += p[(size_t)(c + 56) * 8192];
  }
  for (; c < nchunk; c += 8) a0 += p[(size_t)c * 8192];
  __shared__ float red[256];
  red[threadIdx.x] = ((a0 + a1) + (a2 + a3)) + ((a4 + a5) + (a6 + a7));
  __syncthreads();
  if (threadIdx.x < 32) {
    float s = red[threadIdx.x];
#pragma unroll
    for (int i = 1; i < 8; ++i) s += red[i * 32 + threadIdx.x];
    U[e] = s;
  }
}

// ---------------------------------------------------------------- k_project
__global__ __launch_bounds__(256) void k_project(
    const float* __restrict__ U, const float* __restrict__ pS,
    const float* __restrict__ Wq, const float* __restrict__ bq,
    const float* __restrict__ Wk, const float* __restrict__ bk,
    const float* __restrict__ Wv, const float* __restrict__ bv,
    const float* __restrict__ ev, const float* __restrict__ bb,
    const float* __restrict__ fw,
    float* __restrict__ Qfg, float* __restrict__ Kfg, float* __restrict__ Vfg) {
  int blk = blockIdx.x;                    // b*32 + k
  int k = blk & 31;
  int t = threadIdx.x;
  __shared__ __align__(16) float u[256];
  __shared__ float red[256];
  u[t] = U[(size_t)blk * 256 + t];
  red[t] = pS[t * 32 + k];
  __syncthreads();
#pragma unroll
  for (int off = 128; off > 0; off >>= 1) {
    if (t < off) red[t] += red[t + off];
    __syncthreads();
  }
  float sk = red[0];

  // filter response — FP64 to match numpy ref branch semantics
  float mnf = ev[0], mxf = ev[0];
#pragma unroll
  for (int i = 1; i < 32; ++i) { float v = ev[i]; mnf = fminf(mnf, v); mxf = fmaxf(mxf, v); }
  double mn = (double)mnf, mx = (double)mxf;
  double lam = ((double)ev[k] - mn) / (mx - mn + 1e-8);
  int h = t >> 5;
  float g = 0.f;
#pragma unroll
  for (int i = 0; i < 3; ++i) {
    double lo = (double)bb[h * 4 + i], hi = (double)bb[h * 4 + i + 1];
    if (lam >= lo && lam < hi) g = fw[(h * 3 + i) * 32 + k];
  }

  const float4* u4 = reinterpret_cast<const float4*>(u);
  const float4* wq4 = reinterpret_cast<const float4*>(Wq) + (size_t)t * 64;
  const float4* wk4 = reinterpret_cast<const float4*>(Wk) + (size_t)t * 64;
  const float4* wv4 = reinterpret_cast<const float4*>(Wv) + (size_t)t * 64;
  float aq = 0.f, ak = 0.f, av = 0.f;
#pragma unroll 4
  for (int j = 0; j < 64; ++j) {
    float4 uv = u4[j];
    float4 q = wq4[j], kk = wk4[j], vv = wv4[j];
    aq = fmaf(uv.x, q.x, aq);  aq = fmaf(uv.y, q.y, aq);
    aq = fmaf(uv.z, q.z, aq);  aq = fmaf(uv.w, q.w, aq);
    ak = fmaf(uv.x, kk.x, ak); ak = fmaf(uv.y, kk.y, ak);
    ak = fmaf(uv.z, kk.z, ak); ak = fmaf(uv.w, kk.w, ak);
    av = fmaf(uv.x, vv.x, av); av = fmaf(uv.y, vv.y, av);
    av = fmaf(uv.z, vv.z, av); av = fmaf(uv.w, vv.w, av);
  }
  Qfg[(size_t)blk * 256 + t] = (aq + bq[t] * sk) * g;
  Kfg[(size_t)blk * 256 + t] = (ak + bk[t] * sk) * g;
  Vfg[(size_t)blk * 256 + t] = (av + bv[t] * sk) * g;
}

// ---------------------------------------------------------------- k_attn
__global__ __launch_bounds__(1024) void k_attn(const float* __restrict__ Qfg,
                                               const float* __restrict__ Kfg,
                                               const float* __restrict__ Vfg,
                                               float* __restrict__ of) {
  int blk = blockIdx.x;                    // b*8 + h
  int b = blk >> 3, h = blk & 7;
  int tid = threadIdx.x;
  int row = tid >> 5, col = tid & 31;
  __shared__ float Q[32][33], Kt[32][33], V[32][33], A[32][33];
  size_t base = (size_t)b * 32 * 256 + h * 32;
  Q[row][col]  = Qfg[base + row * 256 + col];
  Kt[row][col] = Kfg[base + row * 256 + col];
  V[row][col]  = Vfg[base + row * 256 + col];
  __syncthreads();
  float sc = 0.f;
#pragma unroll
  for (int d0 = 0; d0 < 32; ++d0) sc = fmaf(Q[row][d0], Kt[col][d0], sc);
  sc *= 0.17677669529663687f;              // 1/sqrt(32)
  float m = sc;
#pragma unroll
  for (int o = 16; o > 0; o >>= 1) m = fmaxf(m, __shfl_xor(m, o, 32));
  float p = expf(sc - m);
  float su = p;
#pragma unroll
  for (int o = 16; o > 0; o >>= 1) su += __shfl_xor(su, o, 32);
  A[row][col] = p / su;
  __syncthreads();
  float o_ = 0.f;
#pragma unroll
  for (int l = 0; l < 32; ++l) o_ = fmaf(A[row][l], V[l][col], o_);
  of[base + row * 256 + col] = o_;
}

// ---------------------------------------------------------------- k_expand
// out[b,n,d] = sum_k E[n,k]*of[b,k,d]. 4 waves (bb = w&1 batch, dh = w>>1
// d-half); lane owns d-pair. of in 32 float2 regs; E chunk (8 KB) staged
// reg->LDS ONCE, read per row via broadcast ds_read (lgkm — store stream
// (vmcnt) never waited on inside the loop). float2 stores, 512B/wave-instr.
__global__ __launch_bounds__(256) void k_expand(const float* __restrict__ E,
                                                const float* __restrict__ of,
                                                float* __restrict__ out,
                                                int N, int rows) {
  int n0 = blockIdx.x * rows;
  int n1 = n0 + rows; if (n1 > N) n1 = N;
  if (n1 <= n0) return;
  int nr = n1 - n0;
  int t = threadIdx.x;
  int w = t >> 6;
  int bb = w & 1;                          // batch
  int dh = w >> 1;                         // d-half
  int lane = t & 63;

  __shared__ __align__(16) float4 es[512]; // 64 rows x 8 f4 = 8 KB
  {
    const float4* e4 = reinterpret_cast<const float4*>(E);
    int f0 = t, f1 = t + 256;
    int r0 = n0 + (f0 >> 3); if (r0 > N - 1) r0 = N - 1;
    int r1 = n0 + (f1 >> 3); if (r1 > N - 1) r1 = N - 1;
    float4 t0 = e4[(size_t)r0 * 8 + (f0 & 7)];
    float4 t1 = e4[(size_t)r1 * 8 + (f1 & 7)];
    es[f0] = t0;
    es[f1] = t1;
  }

  const float* ofb = of + (size_t)bb * 8192 + dh * 128 + 2 * lane;
  float2 v0  = *(const float2*)(ofb +  0*256), v1  = *(const float2*)(ofb +  1*256);
  float2 v2  = *(const float2*)(ofb +  2*256), v3  = *(const float2*)(ofb +  3*256);
  float2 v4  = *(const float2*)(ofb +  4*256), v5  = *(const float2*)(ofb +  5*256);
  float2 v6  = *(const float2*)(ofb +  6*256), v7  = *(const float2*)(ofb +  7*256);
  float2 v8  = *(const float2*)(ofb +  8*256), v9  = *(const float2*)(ofb +  9*256);
  float2 v10 = *(const float2*)(ofb + 10*256), v11 = *(const float2*)(ofb + 11*256);
  float2 v12 = *(const float2*)(ofb + 12*256), v13 = *(const float2*)(ofb + 13*256);
  float2 v14 = *(const float2*)(ofb + 14*256), v15 = *(const float2*)(ofb + 15*256);
  float2 v16 = *(const float2*)(ofb + 16*256), v17 = *(const float2*)(ofb + 17*256);
  float2 v18 = *(const float2*)(ofb + 18*256), v19 = *(const float2*)(ofb + 19*256);
  float2 v20 = *(const float2*)(ofb + 20*256), v21 = *(const float2*)(ofb + 21*256);
  float2 v22 = *(const float2*)(ofb + 22*256), v23 = *(const float2*)(ofb + 23*256);
  float2 v24 = *(const float2*)(ofb + 24*256), v25 = *(const float2*)(ofb + 25*256);
  float2 v26 = *(const float2*)(ofb + 26*256), v27 = *(const float2*)(ofb + 27*256);
  float2 v28 = *(const float2*)(ofb + 28*256), v29 = *(const float2*)(ofb + 29*256);
  float2 v30 = *(const float2*)(ofb + 30*256), v31 = *(const float2*)(ofb + 31*256);

  __syncthreads();

  float* ob = out + (size_t)bb * N * D + dh * 128 + 2 * lane;

#define EX(s, vk, A) { A.x = fmaf(s, vk.x, A.x); A.y = fmaf(s, vk.y, A.y); }
#pragma unroll 2
  for (int r = 0; r < nr; ++r) {
    float4 e0 = es[r*8+0], e1 = es[r*8+1], e2 = es[r*8+2], e3 = es[r*8+3];
    float4 e4_ = es[r*8+4], e5 = es[r*8+5], e6 = es[r*8+6], e7 = es[r*8+7];
    float2 oA = {0.f, 0.f}, oB = {0.f, 0.f};
    EX(e0.x, v0,  oA) EX(e0.y, v1,  oB) EX(e0.z, v2,  oA) EX(e0.w, v3,  oB)
    EX(e1.x, v4,  oA) EX(e1.y, v5,  oB) EX(e1.z, v6,  oA) EX(e1.w, v7,  oB)
    EX(e2.x, v8,  oA) EX(e2.y, v9,  oB) EX(e2.z, v10, oA) EX(e2.w, v11, oB)
    EX(e3.x, v12, oA) EX(e3.y, v13, oB) EX(e3.z, v14, oA) EX(e3.w, v15, oB)
    EX(e4_.x, v16, oA) EX(e4_.y, v17, oB) EX(e4_.z, v18, oA) EX(e4_.w, v19, oB)
    EX(e5.x, v20, oA) EX(e5.y, v21, oB) EX(e5.z, v22, oA) EX(e5.w, v23, oB)
    EX(e6.x, v24, oA) EX(e6.y, v25, oB) EX(e6.z, v26, oA) EX(e6.w, v27, oB)
    EX(e7.x, v28, oA) EX(e7.y, v29, oB) EX(e7.z, v30, oA) EX(e7.w, v31, oB)
    float2 o2;
    o2.x = oA.x + oB.x;
    o2.y = oA.y + oB.y;
    *reinterpret_cast<float2*>(ob + (size_t)(n0 + r) * D) = o2;
  }
#undef EX
}

// ---------------------------------------------------------------- launch
extern "C" void kernel_launch(void* const* d_in, const int* in_sizes, int n_in,
                              void* d_out, int out_size, void* d_ws, size_t ws_size,
                              hipStream_t stream) {
  const float* x  = (const float*)d_in[0];
  const float* E  = (const float*)d_in[1];
  const float* ev = (const float*)d_in[2];
  const float* Wq = (const float*)d_in[3];
  const float* bq = (const float*)d_in[4];
  const float* Wk = (const float*)d_in[5];
  const float* bk = (const float*)d_in[6];
  const float* Wv = (const float*)d_in[7];
  const float* bv = (const float*)d_in[8];
  const float* bb = (const float*)d_in[9];
  const float* fw = (const float*)d_in[10];
  float* out = (float*)d_out;
  float* ws  = (float*)d_ws;

  const int N = in_sizes[1] / 32;          // 50000
  const int B = in_sizes[0] / (N * 256);   // 2

  // workspace layout (floats)
  float* U   = ws;                         // B*32*256 = 16384
  float* Qfg = ws + 16384;
  float* Kfg = ws + 32768;
  float* Vfg = ws + 49152;
  float* of  = ws + 65536;
  float* pS  = ws + 81920;                 // 256*32 = 8192
  float* pU  = ws + 90112;                 // B*nchunk*8192 floats

  // nchunk = 512 -> grid 1024 blocks (4/CU at 36 KB LDS); pU 33.6 MB.
  int nchunk = 512;
  if ((90112 + (size_t)B * nchunk * 8192) * sizeof(float) > ws_size) nchunk = 256;
  int rpc = (N + nchunk - 1) / nchunk;

  k_colsum<<<256, 256, 0, stream>>>(E, pS, N);
  k_partial<<<B * nchunk, 256, 0, stream>>>(x, E, pU, N, nchunk, rpc);
  k_reduce<<<B * 8192 / 32, 256, 0, stream>>>(pU, U, nchunk);
  k_project<<<B * 32, 256, 0, stream>>>(U, pS, Wq, bq, Wk, bk, Wv, bv,
                                        ev, bb, fw, Qfg, Kfg, Vfg);
  k_attn<<<B * 8, 1024, 0, stream>>>(Qfg, Kfg, Vfg, of);
  int rows = 64;
  int nbr = (N + rows - 1) / rows;
  k_expand<<<nbr, 256, 0, stream>>>(E, of, out, N, rows);
}